// Round 6
// baseline (98.467 us; speedup 1.0000x reference)
//
#include <hip/hip_runtime.h>
#include <stdint.h>

#define N_ROWS 65536
#define K_CODES 1024
#define D 64
#define OUT_ELEMS 4194304
#define LOSS_SCALE (1.25f / 4194304.0f)
#define ROWS_PER_BLOCK 256
#define GRID_DIST (N_ROWS / ROWS_PER_BLOCK)  // 256 blocks = 1/CU
#define LDS_BYTES 135168                     // 128K codebook + 4K e2 (dynamic)

typedef short short8 __attribute__((ext_vector_type(8)));
typedef float f32x4 __attribute__((ext_vector_type(4)));

__device__ __forceinline__ unsigned short f2bf(float f) {
    unsigned int u = __float_as_uint(f);
    return (unsigned short)((u + 0x7fffu + ((u >> 16) & 1u)) >> 16);  // RNE
}

#define GLOAD_LDS16(g, l)                                                          \
    __builtin_amdgcn_global_load_lds((const __attribute__((address_space(1))) void*)(g), \
                                     (__attribute__((address_space(3))) void*)(l), 16, 0, 0)

// Prep: ebm2 = bf16(-2*emb); e2 = ||e_k||^2 fp32-exact.
#define ECH (K_CODES * D / 8)  // 8192
__global__ __launch_bounds__(256) void prep_kernel(const float* __restrict__ emb,
                                                   unsigned short* __restrict__ ebm2,
                                                   float* __restrict__ e2) {
    int t = blockIdx.x * 256 + threadIdx.x;
    if (t < ECH) {
        const float4* s = (const float4*)emb;
        float4 a = s[2 * t], b = s[2 * t + 1];
        uint4 o;
        o.x = f2bf(-2.f * a.x) | ((unsigned int)f2bf(-2.f * a.y) << 16);
        o.y = f2bf(-2.f * a.z) | ((unsigned int)f2bf(-2.f * a.w) << 16);
        o.z = f2bf(-2.f * b.x) | ((unsigned int)f2bf(-2.f * b.y) << 16);
        o.w = f2bf(-2.f * b.z) | ((unsigned int)f2bf(-2.f * b.w) << 16);
        ((uint4*)ebm2)[t] = o;
    } else if (t < ECH + K_CODES) {
        int k = t - ECH;
        const float4* e4 = (const float4*)emb;
        float s = 0.f;
#pragma unroll
        for (int i = 0; i < 16; i++) {
            float4 v = e4[k * 16 + i];
            s += v.x * v.x + v.y * v.y + v.z * v.z + v.w * v.w;
        }
        e2[k] = s;
    }
}

// Fused MFMA distance + argmin + quantize-write + loss.
// Full codebook (128K bf16, XOR-swizzled) + e2 (4K) persist in LDS; staged once
// via async global_load_lds, ONE barrier. K-loop has zero vmem / zero barriers.
// Argmin via packed u32 keys: dist_pos = e2 - 2z.e + ||z||^2 + 1 (>0, monotone
// float bits), low 10 bits carry the code index -> v_min3_u32 reduction, numpy
// first-min tie semantics.
__global__ __launch_bounds__(256) void dist_fused_kernel(
        const float* __restrict__ z, const unsigned short* __restrict__ ebm2,
        const float* __restrict__ e2, const float* __restrict__ emb,
        float* __restrict__ out, float* __restrict__ partials) {
    extern __shared__ __align__(16) char smem[];
    const int tid = threadIdx.x;
    const int wave = tid >> 6, lane = tid & 63;
    const int n = lane & 15, q = lane >> 4, nb = n & 7;
    const int wave_row0 = blockIdx.x * ROWS_PER_BLOCK + wave * 64;

    // ---- Stage entire codebook (32 rounds) + e2 (1 round), async ----
    {
        const uint4* gsrc = (const uint4*)ebm2;
#pragma unroll
        for (int r = 0; r < 32; r++) {
            int S = r * 256 + tid;                               // 16B slot
            int P = (S & ~7) | ((S & 7) ^ ((S >> 3) & 7));       // XOR-swizzled source
            char* l = smem + (r * 256 + (tid & ~63)) * 16;       // wave-uniform base
            GLOAD_LDS16(gsrc + P, l);
        }
        GLOAD_LDS16(e2 + tid * 4, smem + 131072 + (tid & ~63) * 16);
    }

    // ---- z: 4 row-sets x 16 rows; fp32 ||z||^2 (exact) + bf16 B-frags ----
    short8 b[4][2];
    float z2c[4];  // full-row ||z||^2 + 1, bit-identical across quads
#pragma unroll
    for (int rs = 0; rs < 4; rs++) {
        const float* zr = z + (size_t)(wave_row0 + rs * 16 + n) * D + q * 8;
        float4 f0 = *(const float4*)(zr);
        float4 f1 = *(const float4*)(zr + 4);
        float4 f2 = *(const float4*)(zr + 32);
        float4 f3 = *(const float4*)(zr + 36);
        float z2p = f0.x*f0.x + f0.y*f0.y + f0.z*f0.z + f0.w*f0.w
                  + f1.x*f1.x + f1.y*f1.y + f1.z*f1.z + f1.w*f1.w
                  + f2.x*f2.x + f2.y*f2.y + f2.z*f2.z + f2.w*f2.w
                  + f3.x*f3.x + f3.y*f3.y + f3.z*f3.z + f3.w*f3.w;
        z2p += __shfl_xor(z2p, 16, 64);
        z2p += __shfl_xor(z2p, 32, 64);   // commutative-only -> exact same bits all quads
        z2c[rs] = z2p + 1.0f;
        short8 lo, hi;
        lo[0] = f2bf(f0.x); lo[1] = f2bf(f0.y); lo[2] = f2bf(f0.z); lo[3] = f2bf(f0.w);
        lo[4] = f2bf(f1.x); lo[5] = f2bf(f1.y); lo[6] = f2bf(f1.z); lo[7] = f2bf(f1.w);
        hi[0] = f2bf(f2.x); hi[1] = f2bf(f2.y); hi[2] = f2bf(f2.z); hi[3] = f2bf(f2.w);
        hi[4] = f2bf(f3.x); hi[5] = f2bf(f3.y); hi[6] = f2bf(f3.z); hi[7] = f2bf(f3.w);
        b[rs][0] = lo; b[rs][1] = hi;
    }

    const int base0 = n * 128 + ((q ^ nb) << 4);
    const int base1 = n * 128 + (((4 | q) ^ nb) << 4);
    const int vq4 = q * 4;
    unsigned int best[4] = {0xFFFFFFFFu, 0xFFFFFFFFu, 0xFFFFFFFFu, 0xFFFFFFFFu};

    __syncthreads();  // staging landed (single drain in the whole kernel)

    // ---- K-loop: 64 tiles, no vmem, no barriers ----
    for (int c = 0; c < 4; c++) {
        const unsigned int kc = c * 256 + vq4;
#pragma unroll
        for (int tl = 0; tl < 16; tl++) {
            const int t = c * 16 + tl;
            short8 a0 = *(const short8*)(smem + t * 2048 + base0);
            short8 a1 = *(const short8*)(smem + t * 2048 + base1);
            f32x4 E = *(const f32x4*)(smem + 131072 + t * 64 + vq4 * 4);  // quad-broadcast
            const unsigned int k0i = kc + tl * 16;
#pragma unroll
            for (int rs = 0; rs < 4; rs++) {
                f32x4 a = E + z2c[rs];  // acc init = ||e||^2 + ||z||^2 + 1 > 0
                a = __builtin_amdgcn_mfma_f32_16x16x32_bf16(a0, b[rs][0], a, 0, 0, 0);
                a = __builtin_amdgcn_mfma_f32_16x16x32_bf16(a1, b[rs][1], a, 0, 0, 0);
#pragma unroll
                for (int r = 0; r < 4; r++) {
                    unsigned int key = (__float_as_uint(a[r]) & 0xFFFFFC00u) | (k0i + r);
                    best[rs] = best[rs] < key ? best[rs] : key;  // -> v_min3_u32 fusion
                }
            }
        }
    }

    // ---- Cross-quad min + loss terms (u32 keys) ----
    float lossl = 0.f;
    int bidx[4];
#pragma unroll
    for (int rs = 0; rs < 4; rs++) {
        unsigned int key = best[rs];
        unsigned int o = (unsigned int)__shfl_xor((int)key, 16, 64);
        key = o < key ? o : key;
        o = (unsigned int)__shfl_xor((int)key, 32, 64);
        key = o < key ? o : key;   // all lanes hold the row's result
        bidx[rs] = (int)(key & 1023u);
        lossl += __uint_as_float(key & 0xFFFFFC00u) - 1.0f;  // ||q-z||^2 (trunc ~2^-13 rel)
    }

    // ---- Epilogue: per-wave gather-write of quantized rows (no z re-read) ----
    const float4* emb4 = (const float4*)emb;
    float4* o4 = (float4*)out + (size_t)wave_row0 * 16;
#pragma unroll
    for (int it = 0; it < 16; it++) {
        int k = __shfl(bidx[it >> 2], (it * 4 + q) & 15, 64);  // idx of row it*4+q
        o4[it * 64 + lane] = emb4[k * 16 + n];
    }

    // ---- Loss: lanes count each row 4x -> 0.25 scale ----
#pragma unroll
    for (int off = 32; off > 0; off >>= 1)
        lossl += __shfl_down(lossl, off, 64);
    __syncthreads();           // all waves done reading codebook before overlay
    float* ps = (float*)smem;
    if (lane == 0) ps[wave] = lossl;
    __syncthreads();
    if (tid == 0) partials[blockIdx.x] = 0.25f * (ps[0] + ps[1] + ps[2] + ps[3]);
}

// Single block: sum 256 partials -> loss (no atomics anywhere).
__global__ __launch_bounds__(256) void loss_kernel(const float* __restrict__ partials,
                                                   float* __restrict__ loss) {
    float s = partials[threadIdx.x];
#pragma unroll
    for (int off = 32; off > 0; off >>= 1)
        s += __shfl_down(s, off, 64);
    __shared__ float ps[4];
    int wave = threadIdx.x >> 6, lane = threadIdx.x & 63;
    if (lane == 0) ps[wave] = s;
    __syncthreads();
    if (threadIdx.x == 0) loss[0] = (ps[0] + ps[1] + ps[2] + ps[3]) * LOSS_SCALE;
}

extern "C" void kernel_launch(void* const* d_in, const int* in_sizes, int n_in,
                              void* d_out, int out_size, void* d_ws, size_t ws_size,
                              hipStream_t stream) {
    const float* z = (const float*)d_in[0];
    const float* emb = (const float*)d_in[1];
    float* out = (float*)d_out;
    float* loss = out + OUT_ELEMS;

    char* ws = (char*)d_ws;
    float* e2 = (float*)ws;                                       // 4 KiB
    unsigned short* ebm2 = (unsigned short*)(ws + 4096);          // 128 KiB
    float* partials = (float*)(ws + 4096 + 131072 + 8192);        // 1 KiB (8K pad)

    // Opt-in for >64KB dynamic LDS (host-side attr, idempotent, not a stream op).
    hipFuncSetAttribute((const void*)dist_fused_kernel,
                        hipFuncAttributeMaxDynamicSharedMemorySize, LDS_BYTES);

    prep_kernel<<<(ECH + K_CODES + 255) / 256, 256, 0, stream>>>(emb, ebm2, e2);
    dist_fused_kernel<<<GRID_DIST, 256, LDS_BYTES, stream>>>(z, ebm2, e2, emb, out, partials);
    loss_kernel<<<1, 256, 0, stream>>>(partials, loss);
}